// Round 22
// baseline (166.789 us; speedup 1.0000x reference)
//
#include <hip/hip_runtime.h>
#include <cstdint>
#include <cstddef>

#define NH  16
#define HD  64
#define DM  1024
#define SB  2048
#define WIN 512

typedef _Float16 half8  __attribute__((ext_vector_type(8)));
typedef _Float16 half4  __attribute__((ext_vector_type(4)));
typedef float    f32x4  __attribute__((ext_vector_type(4)));

// global_load_lds: LDS dest must be WAVE-UNIFORM (hw adds lane*16); global src is per-lane.
#define GLL16(gp, lp) __builtin_amdgcn_global_load_lds( \
    (const __attribute__((address_space(1))) void*)(gp), \
    (__attribute__((address_space(3))) void*)(lp), 16, 0, 0)

// Zero-fill of the out-of-band region. Boundaries 128B-aligned to match the
// attn band writes: lo = t0-512-16*par, hi = t0+32+16*par (par = q-tile parity).
__device__ __forceinline__ void zero_fill_role(float* zbase, int plane0, int nplanes,
                                               int fb, int nfb) {
  const int nrows = nplanes << 11;
  const f32x4 z4 = {0.f, 0.f, 0.f, 0.f};
  const int tid = threadIdx.x;
  const int step = blockDim.x * 4;
  for (int rr = fb; rr < nrows; rr += nfb) {
    const int bh = plane0 + (rr >> 11), i = rr & 2047;
    float* rowp = zbase + ((size_t)bh << 22) + ((size_t)i << 11);
    const int t0i = i & ~15;
    const int par = (t0i >> 4) & 1;
    int lo = t0i - 512 - 16 * par; if (lo < 0) lo = 0;
    int hi = t0i + 32 + 16 * par;  if (hi > SB) hi = SB;
    for (int c = tid * 4; c < lo; c += step)
      __builtin_nontemporal_store(z4, (f32x4*)(rowp + c));
    for (int c = hi + tid * 4; c < SB; c += step)
      __builtin_nontemporal_store(z4, (f32x4*)(rowp + c));
  }
}

// ---------------- merged preprocessing: x f32->f16, W f32->f16 transposed ----------------
__global__ void k_pre(const float* __restrict__ x,
                      const float* __restrict__ Wq, const float* __restrict__ Wk,
                      const float* __restrict__ Wv, const float* __restrict__ Wo,
                      _Float16* __restrict__ xh, _Float16* __restrict__ Wt) {
  __shared__ float t[64][68];
  const int bid = blockIdx.x, tid = threadIdx.x;
  if (bid < 2048) {
    const int i = (bid * 256 + tid) * 8;
    const float4 a = *(const float4*)(x + i);
    const float4 b = *(const float4*)(x + i + 4);
    half8 o = { (_Float16)a.x, (_Float16)a.y, (_Float16)a.z, (_Float16)a.w,
                (_Float16)b.x, (_Float16)b.y, (_Float16)b.z, (_Float16)b.w };
    *(half8*)(xh + i) = o;
    return;
  }
  const int tt = bid - 2048;
  const int z = tt >> 8, r2 = tt & 255;
  const int k0 = (r2 >> 4) * 64, n0 = (r2 & 15) * 64;
  const float* src = (z == 0) ? Wq : (z == 1) ? Wk : (z == 2) ? Wv : Wo;
  _Float16* dst = Wt + (size_t)z * DM * DM;
  #pragma unroll
  for (int i = 0; i < 4; ++i) {
    const int idx = i * 1024 + tid * 4;
    const int r = idx >> 6, c = idx & 63;
    const float4 v = *(const float4*)(src + (size_t)(k0 + r) * DM + n0 + c);
    *(float4*)(&t[r][c]) = v;
  }
  __syncthreads();
  #pragma unroll
  for (int i = 0; i < 4; ++i) {
    const int idx = i * 1024 + tid * 4;
    const int nr = idx >> 6, kc = idx & 63;
    half4 o = { (_Float16)t[kc + 0][nr], (_Float16)t[kc + 1][nr],
                (_Float16)t[kc + 2][nr], (_Float16)t[kc + 3][nr] };
    *(half4*)(dst + (size_t)(n0 + nr) * DM + k0 + kc) = o;
  }
}

// ---------------- GEMM: C[M,N] = A[M,K]h * Wt[N,K]h + bias; M=4096,N=K=1024 ----------------
template<bool F32OUT>
__global__ __launch_bounds__(256, 4) void k_gemm(
    const _Float16* __restrict__ A, const _Float16* __restrict__ Wt,
    const float* __restrict__ b0, const float* __restrict__ b1, const float* __restrict__ b2,
    void* __restrict__ outv, _Float16* __restrict__ Vt, float scale0,
    float* __restrict__ zbase, int plane0, int nplanes)
{
  __shared__ _Float16 As[128 * 64];
  __shared__ _Float16 Bs[128 * 64];
  if (blockIdx.x >= 32) {
    const int FBn = gridDim.x - 32;
    const int fb  = (blockIdx.x - 32) + FBn * (blockIdx.y + gridDim.y * blockIdx.z);
    zero_fill_role(zbase, plane0, nplanes, fb, FBn * gridDim.y * gridDim.z);
    return;
  }

  const int z = blockIdx.z;
  const _Float16* Wz = Wt + (size_t)z * DM * DM;
  const float* bias = (z == 0) ? b0 : (z == 1) ? b1 : b2;
  const float scale = (z == 0) ? scale0 : 1.0f;
  const int m0 = blockIdx.x * 128, n0 = blockIdx.y * 128;
  const int tid = threadIdx.x, lane = tid & 63, wid = tid >> 6;
  const int g = lane >> 4, li = lane & 15;
  const int wr = (wid & 1) * 64, wc = (wid >> 1) * 64;

  f32x4 acc[4][4] = {};

  for (int kt = 0; kt < 16; ++kt) {
    const int kb = kt * 64;
    #pragma unroll
    for (int i = 0; i < 4; ++i) {
      const int c = wid + 4 * i;
      const int off = c * 1024 + lane * 16;
      const int r = off >> 7;
      const int cb = off & 127;
      const int sc_ = cb ^ ((r & 7) << 4);
      GLL16(A  + (size_t)(m0 + r) * DM + kb + (sc_ >> 1), (char*)As + c * 1024);
      GLL16(Wz + (size_t)(n0 + r) * DM + kb + (sc_ >> 1), (char*)Bs + c * 1024);
    }
    __syncthreads();
    #pragma unroll
    for (int kk = 0; kk < 2; ++kk) {
      half8 bf[4];
      #pragma unroll
      for (int ni = 0; ni < 4; ++ni) {
        const int r = wc + ni * 16 + li;
        const int cbyte = (kk * 64 + g * 16) ^ ((r & 7) << 4);
        bf[ni] = *(const half8*)((const char*)Bs + r * 128 + cbyte);
      }
      #pragma unroll
      for (int mi = 0; mi < 4; ++mi) {
        const int r = wr + mi * 16 + li;
        const int cbyte = (kk * 64 + g * 16) ^ ((r & 7) << 4);
        const half8 af = *(const half8*)((const char*)As + r * 128 + cbyte);
        #pragma unroll
        for (int ni = 0; ni < 4; ++ni)
          acc[mi][ni] = __builtin_amdgcn_mfma_f32_16x16x32_f16(af, bf[ni], acc[mi][ni], 0, 0, 0);
      }
    }
    __syncthreads();
  }

  float bv[4];
  #pragma unroll
  for (int ni = 0; ni < 4; ++ni) bv[ni] = bias[n0 + wc + ni * 16 + li];

  if (!F32OUT && z == 2) {
    #pragma unroll
    for (int mi = 0; mi < 4; ++mi)
      #pragma unroll
      for (int ni = 0; ni < 4; ++ni) {
        const int col = n0 + wc + ni * 16 + li;
        const int h2 = col >> 6, d = col & 63;
        const int row0 = m0 + wr + mi * 16 + g * 4;
        const int bb = row0 >> 11, s0 = row0 & 2047;
        half4 o = { (_Float16)(acc[mi][ni][0] + bv[ni]), (_Float16)(acc[mi][ni][1] + bv[ni]),
                    (_Float16)(acc[mi][ni][2] + bv[ni]), (_Float16)(acc[mi][ni][3] + bv[ni]) };
        *(half4*)(Vt + (size_t)((bb * NH + h2) * HD + d) * SB + s0) = o;
      }
    return;
  }

  #pragma unroll
  for (int mi = 0; mi < 4; ++mi)
    #pragma unroll
    for (int ni = 0; ni < 4; ++ni)
      #pragma unroll
      for (int reg = 0; reg < 4; ++reg) {
        const int row = m0 + wr + mi * 16 + g * 4 + reg;
        const int col = n0 + wc + ni * 16 + li;
        const float v = (acc[mi][ni][reg] + bv[ni]) * scale;
        if (F32OUT) ((float*)outv)[(size_t)row * DM + col] = v;
        else ((_Float16*)outv + (size_t)z * 4096 * 1024)[(size_t)row * DM + col] = (_Float16)v;
      }
}

// ---------------- sliding-window attention: r21 + unconditional early PV ----------------
// Changes vs r21 (each attacking the remaining serial load-latency chain):
//  1. PV loop is UNCONDITIONAL: pp[] is zero-init and only written for valid slots, so
//     invalid chunks contribute pa=0 to the MFMA; jb already clamped. No `continue`s ->
//     all 20 V loads are hoistable/pipelinable (was 5 serial exposures).
//  2. PV moved BEFORE the softmax sync (it consumes raw pp only; rinv applied in the
//     epilogue) -> one __syncthreads covers both sred and ored (removes a barrier) and
//     V-load latency overlaps the other waves' sync arrival.
//  3. Band writeback + attb epilogue after the single sync (unchanged logic).
__global__ __launch_bounds__(256, 3) void k_attn(
    const _Float16* __restrict__ Q, const _Float16* __restrict__ K,
    const _Float16* __restrict__ Vt, float* __restrict__ Wout,
    _Float16* __restrict__ attb, int plane0, int nplanes)
{
  __shared__ float sred[4][16];
  __shared__ f32x4 ored[3][64][4];
  __shared__ _Float16 pw[16][584];
  if (blockIdx.x >= 128) {
    const int FBn = gridDim.x - 128;
    const int fb  = (blockIdx.x - 128) + FBn * (blockIdx.y + gridDim.y * blockIdx.z);
    zero_fill_role(Wout, plane0, nplanes, fb, FBn * gridDim.y * gridDim.z);
    return;
  }

  const int b = blockIdx.z, h = blockIdx.y;
  const int tid = threadIdx.x, lane = tid & 63, wid = tid >> 6;
  const int g = lane >> 4, li = lane & 15;
  const int qt = blockIdx.x;
  const int t0 = qt * 16;

  half8 qf[2];
  #pragma unroll
  for (int kk = 0; kk < 2; ++kk)
    qf[kk] = *(const half8*)(Q + (size_t)(b * SB + t0 + li) * DM + h * HD + kk * 32 + g * 8);

  const int kt_lo = qt - 32;
  const int d1 = kt_lo & 1;              // parity (1 for odd q-tiles)
  const int ktA0 = kt_lo - d1;           // even chunk base
  const _Float16* kb_ = K + (size_t)b * SB * DM + (size_t)h * HD;

  // chunk ownership: 17+d1 chunks over 4 waves (exact partition of slots [-d1, 34+d1))
  const int c_base = (wid == 0) ? 0 : (wid == 1) ? 5 : (wid == 2) ? (9 + d1) : (13 + d1);
  const int c_cnt  = (wid == 0) ? 5 : (wid == 1) ? (4 + d1) : 4;
  const int it_lo  = 2 * c_base - d1;
  const int it_n   = 2 * c_cnt;

  // ---- pass 1: QK with batched prefetch (5 tiles/batch, clamped addresses) ----
  half4 pp[10] = {};
  float s = 0.f;
  #pragma unroll
  for (int hb = 0; hb < 2; ++hb) {
    half8 kf[5][2];
    #pragma unroll
    for (int j = 0; j < 5; ++j) {
      int kt = kt_lo + it_lo + hb * 5 + j;
      kt = kt < 0 ? 0 : (kt > 127 ? 127 : kt);          // clamp -> unconditional load
      const _Float16* src = kb_ + (size_t)(kt * 16 + li) * DM + g * 8;
      kf[j][0] = *(const half8*)(src);
      kf[j][1] = *(const half8*)(src + 32);
    }
    #pragma unroll
    for (int j = 0; j < 5; ++j) {
      const int itl = hb * 5 + j;
      if (itl >= it_n) continue;                        // wave-uniform
      const int it = it_lo + itl;
      const int kt = kt_lo + it;
      const int scol = (it + d1) * 16 + g * 4;          // pw col of this slot
      if (it < 0 || it > 32 || kt < 0) {                // pad slot: exact zeros
        *(half4*)(&pw[li][scol]) = (half4){(_Float16)0.f, (_Float16)0.f, (_Float16)0.f, (_Float16)0.f};
        continue;
      }
      f32x4 a = {0.f, 0.f, 0.f, 0.f};
      a = __builtin_amdgcn_mfma_f32_16x16x32_f16(kf[j][0], qf[0], a, 0, 0, 0);
      a = __builtin_amdgcn_mfma_f32_16x16x32_f16(kf[j][1], qf[1], a, 0, 0, 0);
      float p0 = exp2f(a[0]), p1 = exp2f(a[1]), p2 = exp2f(a[2]), p3 = exp2f(a[3]);
      if (it == 0) {           // window tail: keep iff g*4+r > li
        p0 = (g * 4 + 0 > li) ? p0 : 0.f;
        p1 = (g * 4 + 1 > li) ? p1 : 0.f;
        p2 = (g * 4 + 2 > li) ? p2 : 0.f;
        p3 = (g * 4 + 3 > li) ? p3 : 0.f;
      }
      if (it == 32) {          // causal diagonal: keep iff g*4+r <= li
        p0 = (g * 4 + 0 <= li) ? p0 : 0.f;
        p1 = (g * 4 + 1 <= li) ? p1 : 0.f;
        p2 = (g * 4 + 2 <= li) ? p2 : 0.f;
        p3 = (g * 4 + 3 <= li) ? p3 : 0.f;
      }
      s += (p0 + p1) + (p2 + p3);
      half4 ph = {(_Float16)p0, (_Float16)p1, (_Float16)p2, (_Float16)p3};
      pp[itl] = ph;
      *(half4*)(&pw[li][scol]) = ph;
    }
  }

  // ---- PV immediately (unconditional; invalid slots have pp==0 -> pa==0) ----
  const _Float16* vb = Vt + (size_t)(b * NH + h) * HD * SB;
  f32x4 oacc[4] = {};
  #pragma unroll
  for (int cl = 0; cl < 5; ++cl) {
    const int ktA = ktA0 + 2 * (c_base + cl);
    float pAf[4], pBf[4];
    #pragma unroll
    for (int r = 0; r < 4; ++r) { pAf[r] = (float)pp[2 * cl][r]; pBf[r] = (float)pp[2 * cl + 1][r]; }
    half8 pa;
    #pragma unroll
    for (int c8 = 0; c8 < 8; ++c8) {
      const int srcl = ((2 * (g & 1) + (c8 >> 2)) << 4) + li;
      const float va  = __shfl(pAf[c8 & 3], srcl);
      const float vb2 = __shfl(pBf[c8 & 3], srcl);
      pa[c8] = (_Float16)(g < 2 ? va : vb2);
    }
    int jb = ktA * 16 + g * 8;
    jb = jb < 0 ? 0 : (jb > SB - 8 ? SB - 8 : jb);
    #pragma unroll
    for (int dt = 0; dt < 4; ++dt) {
      half8 vf = *(const half8*)(vb + (size_t)(dt * 16 + li) * SB + jb);
      oacc[dt] = __builtin_amdgcn_mfma_f32_16x16x32_f16(pa, vf, oacc[dt], 0, 0, 0);
    }
  }

  // ---- single sync: sred (softmax denom) + ored (PV partials) ----
  s += __shfl_xor(s, 16);
  s += __shfl_xor(s, 32);
  if (lane < 16) sred[wid][lane] = s;
  if (wid > 0) {
    #pragma unroll
    for (int dt = 0; dt < 4; ++dt) ored[wid - 1][lane][dt] = oacc[dt];
  }
  __syncthreads();
  const float rinv = 1.0f / (sred[0][li] + sred[1][li] + sred[2][li] + sred[3][li]);

  // ---- band writeback: full-line nt streaming (wave handles rows wid*4..wid*4+3) ----
  {
    float* wb = Wout + (size_t)(b * NH + h) * SB * SB;
    const int W4 = 136 + 8 * d1;        // 4-float chunks per row
    const int cs = ktA0 * 16;           // global col of pw col 0 (128B-aligned)
    #pragma unroll
    for (int rr = 0; rr < 4; ++rr) {
      const int r_ = wid * 4 + rr;
      const float rv = 1.0f / (sred[0][r_] + sred[1][r_] + sred[2][r_] + sred[3][r_]);
      float* dst = wb + (size_t)(t0 + r_) * SB;
      #pragma unroll
      for (int p = 0; p < 3; ++p) {
        const int idx = p * 64 + lane;
        if (idx < W4) {
          const int gc = cs + 4 * idx;
          if (gc >= 0 && gc < SB) {
            const half4 hv = *(const half4*)(&pw[r_][4 * idx]);
            f32x4 w = {(float)hv[0] * rv, (float)hv[1] * rv, (float)hv[2] * rv, (float)hv[3] * rv};
            __builtin_nontemporal_store(w, (f32x4*)(dst + gc));
          }
        }
      }
    }
  }

  // ---- cross-wave PV reduction + output (wid 0) ----
  if (wid == 0) {
    #pragma unroll
    for (int dt = 0; dt < 4; ++dt)
      oacc[dt] += ored[0][lane][dt] + ored[1][lane][dt] + ored[2][lane][dt];
    #pragma unroll
    for (int dt = 0; dt < 4; ++dt)
      #pragma unroll
      for (int r = 0; r < 4; ++r) {
        const float rr = __shfl(rinv, g * 4 + r);
        attb[(size_t)(b * SB + t0 + g * 4 + r) * DM + h * HD + dt * 16 + li] =
            (_Float16)(oacc[dt][r] * rr);
      }
  }
}

extern "C" void kernel_launch(void* const* d_in, const int* in_sizes, int n_in,
                              void* d_out, int out_size, void* d_ws, size_t ws_size,
                              hipStream_t stream) {
  (void)in_sizes; (void)n_in; (void)out_size; (void)ws_size;
  const float* x  = (const float*)d_in[0];
  const float* Wq = (const float*)d_in[1];
  const float* bq = (const float*)d_in[2];
  const float* Wk = (const float*)d_in[3];
  const float* bk = (const float*)d_in[4];
  const float* Wv = (const float*)d_in[5];
  const float* bv = (const float*)d_in[6];
  const float* Wo = (const float*)d_in[7];
  const float* bo = (const float*)d_in[8];

  char* ws = (char*)d_ws;
  _Float16* xh   = (_Float16*)(ws);                        // 8 MB
  _Float16* Wt   = (_Float16*)(ws + (size_t)8  * 1048576); // 8 MB
  _Float16* QKV  = (_Float16*)(ws + (size_t)16 * 1048576); // 16 MB (Q,K planes)
  _Float16* Vt   = (_Float16*)(ws + (size_t)32 * 1048576); // 8 MB
  _Float16* attb = (_Float16*)(ws + (size_t)40 * 1048576); // 8 MB

  float* out   = (float*)d_out;
  float* Wattn = out + (size_t)2 * SB * DM;   // attention-weights output region

  // Q pre-scaled by 0.125*log2(e) so attention can use exp2 directly.
  const float qscale = 0.125f * 1.4426950408889634f;
  const _Float16* Kp = QKV + (size_t)4096 * 1024;

  k_pre<<<dim3(3072), dim3(256), 0, stream>>>(x, Wq, Wk, Wv, Wo, xh, Wt);
  // QKV GEMM (768 compute blocks) + 192 fill blocks, planes [0,12)
  k_gemm<false><<<dim3(40, 8, 3), dim3(256), 0, stream>>>(xh, Wt, bq, bk, bv, (void*)QKV, Vt, qscale, Wattn, 0, 12);
  // attn (4096 compute blocks) + 512 fill blocks, planes [12,24)
  k_attn<<<dim3(144, 16, 2), dim3(256), 0, stream>>>(QKV, Kp, Vt, Wattn, attb, 12, 12);
  // O GEMM (256 compute blocks) + 128 fill blocks, planes [24,32)
  k_gemm<true><<<dim3(48, 8, 1), dim3(256), 0, stream>>>(attb, Wt + (size_t)3 * DM * DM, bo, bo, bo, (void*)out, nullptr, 1.0f, Wattn, 24, 8);
}

// Round 23
// 165.379 us; speedup vs baseline: 1.0085x; 1.0085x over previous
//
#include <hip/hip_runtime.h>
#include <cstdint>
#include <cstddef>

#define NH  16
#define HD  64
#define DM  1024
#define SB  2048
#define WIN 512

typedef _Float16 half8  __attribute__((ext_vector_type(8)));
typedef _Float16 half4  __attribute__((ext_vector_type(4)));
typedef float    f32x4  __attribute__((ext_vector_type(4)));

// global_load_lds: LDS dest must be WAVE-UNIFORM (hw adds lane*16); global src is per-lane.
#define GLL16(gp, lp) __builtin_amdgcn_global_load_lds( \
    (const __attribute__((address_space(1))) void*)(gp), \
    (__attribute__((address_space(3))) void*)(lp), 16, 0, 0)

// Zero-fill of the out-of-band region. Boundaries 128B-aligned to match the
// attn band writes: lo = t0-512-16*par, hi = t0+32+16*par (par = q-tile parity).
__device__ __forceinline__ void zero_fill_role(float* zbase, int plane0, int nplanes,
                                               int fb, int nfb) {
  const int nrows = nplanes << 11;
  const f32x4 z4 = {0.f, 0.f, 0.f, 0.f};
  const int tid = threadIdx.x;
  const int step = blockDim.x * 4;
  for (int rr = fb; rr < nrows; rr += nfb) {
    const int bh = plane0 + (rr >> 11), i = rr & 2047;
    float* rowp = zbase + ((size_t)bh << 22) + ((size_t)i << 11);
    const int t0i = i & ~15;
    const int par = (t0i >> 4) & 1;
    int lo = t0i - 512 - 16 * par; if (lo < 0) lo = 0;
    int hi = t0i + 32 + 16 * par;  if (hi > SB) hi = SB;
    for (int c = tid * 4; c < lo; c += step)
      __builtin_nontemporal_store(z4, (f32x4*)(rowp + c));
    for (int c = hi + tid * 4; c < SB; c += step)
      __builtin_nontemporal_store(z4, (f32x4*)(rowp + c));
  }
}

// ---------------- merged preprocessing: x f32->f16, W f32->f16 transposed ----------------
__global__ void k_pre(const float* __restrict__ x,
                      const float* __restrict__ Wq, const float* __restrict__ Wk,
                      const float* __restrict__ Wv, const float* __restrict__ Wo,
                      _Float16* __restrict__ xh, _Float16* __restrict__ Wt) {
  __shared__ float t[64][68];
  const int bid = blockIdx.x, tid = threadIdx.x;
  if (bid < 2048) {
    const int i = (bid * 256 + tid) * 8;
    const float4 a = *(const float4*)(x + i);
    const float4 b = *(const float4*)(x + i + 4);
    half8 o = { (_Float16)a.x, (_Float16)a.y, (_Float16)a.z, (_Float16)a.w,
                (_Float16)b.x, (_Float16)b.y, (_Float16)b.z, (_Float16)b.w };
    *(half8*)(xh + i) = o;
    return;
  }
  const int tt = bid - 2048;
  const int z = tt >> 8, r2 = tt & 255;
  const int k0 = (r2 >> 4) * 64, n0 = (r2 & 15) * 64;
  const float* src = (z == 0) ? Wq : (z == 1) ? Wk : (z == 2) ? Wv : Wo;
  _Float16* dst = Wt + (size_t)z * DM * DM;
  #pragma unroll
  for (int i = 0; i < 4; ++i) {
    const int idx = i * 1024 + tid * 4;
    const int r = idx >> 6, c = idx & 63;
    const float4 v = *(const float4*)(src + (size_t)(k0 + r) * DM + n0 + c);
    *(float4*)(&t[r][c]) = v;
  }
  __syncthreads();
  #pragma unroll
  for (int i = 0; i < 4; ++i) {
    const int idx = i * 1024 + tid * 4;
    const int nr = idx >> 6, kc = idx & 63;
    half4 o = { (_Float16)t[kc + 0][nr], (_Float16)t[kc + 1][nr],
                (_Float16)t[kc + 2][nr], (_Float16)t[kc + 3][nr] };
    *(half4*)(dst + (size_t)(n0 + nr) * DM + k0 + kc) = o;
  }
}

// ---------------- GEMM: C[M,N] = A[M,K]h * Wt[N,K]h + bias; M=4096,N=K=1024 ----------------
template<bool F32OUT>
__global__ __launch_bounds__(256, 4) void k_gemm(
    const _Float16* __restrict__ A, const _Float16* __restrict__ Wt,
    const float* __restrict__ b0, const float* __restrict__ b1, const float* __restrict__ b2,
    void* __restrict__ outv, _Float16* __restrict__ Vt, float scale0,
    float* __restrict__ zbase, int plane0, int nplanes)
{
  __shared__ _Float16 As[128 * 64];
  __shared__ _Float16 Bs[128 * 64];
  if (blockIdx.x >= 32) {
    const int FBn = gridDim.x - 32;
    const int fb  = (blockIdx.x - 32) + FBn * (blockIdx.y + gridDim.y * blockIdx.z);
    zero_fill_role(zbase, plane0, nplanes, fb, FBn * gridDim.y * gridDim.z);
    return;
  }

  const int z = blockIdx.z;
  const _Float16* Wz = Wt + (size_t)z * DM * DM;
  const float* bias = (z == 0) ? b0 : (z == 1) ? b1 : b2;
  const float scale = (z == 0) ? scale0 : 1.0f;
  const int m0 = blockIdx.x * 128, n0 = blockIdx.y * 128;
  const int tid = threadIdx.x, lane = tid & 63, wid = tid >> 6;
  const int g = lane >> 4, li = lane & 15;
  const int wr = (wid & 1) * 64, wc = (wid >> 1) * 64;

  f32x4 acc[4][4] = {};

  for (int kt = 0; kt < 16; ++kt) {
    const int kb = kt * 64;
    #pragma unroll
    for (int i = 0; i < 4; ++i) {
      const int c = wid + 4 * i;
      const int off = c * 1024 + lane * 16;
      const int r = off >> 7;
      const int cb = off & 127;
      const int sc_ = cb ^ ((r & 7) << 4);
      GLL16(A  + (size_t)(m0 + r) * DM + kb + (sc_ >> 1), (char*)As + c * 1024);
      GLL16(Wz + (size_t)(n0 + r) * DM + kb + (sc_ >> 1), (char*)Bs + c * 1024);
    }
    __syncthreads();
    #pragma unroll
    for (int kk = 0; kk < 2; ++kk) {
      half8 bf[4];
      #pragma unroll
      for (int ni = 0; ni < 4; ++ni) {
        const int r = wc + ni * 16 + li;
        const int cbyte = (kk * 64 + g * 16) ^ ((r & 7) << 4);
        bf[ni] = *(const half8*)((const char*)Bs + r * 128 + cbyte);
      }
      #pragma unroll
      for (int mi = 0; mi < 4; ++mi) {
        const int r = wr + mi * 16 + li;
        const int cbyte = (kk * 64 + g * 16) ^ ((r & 7) << 4);
        const half8 af = *(const half8*)((const char*)As + r * 128 + cbyte);
        #pragma unroll
        for (int ni = 0; ni < 4; ++ni)
          acc[mi][ni] = __builtin_amdgcn_mfma_f32_16x16x32_f16(af, bf[ni], acc[mi][ni], 0, 0, 0);
      }
    }
    __syncthreads();
  }

  float bv[4];
  #pragma unroll
  for (int ni = 0; ni < 4; ++ni) bv[ni] = bias[n0 + wc + ni * 16 + li];

  if (!F32OUT && z == 2) {
    #pragma unroll
    for (int mi = 0; mi < 4; ++mi)
      #pragma unroll
      for (int ni = 0; ni < 4; ++ni) {
        const int col = n0 + wc + ni * 16 + li;
        const int h2 = col >> 6, d = col & 63;
        const int row0 = m0 + wr + mi * 16 + g * 4;
        const int bb = row0 >> 11, s0 = row0 & 2047;
        half4 o = { (_Float16)(acc[mi][ni][0] + bv[ni]), (_Float16)(acc[mi][ni][1] + bv[ni]),
                    (_Float16)(acc[mi][ni][2] + bv[ni]), (_Float16)(acc[mi][ni][3] + bv[ni]) };
        *(half4*)(Vt + (size_t)((bb * NH + h2) * HD + d) * SB + s0) = o;
      }
    return;
  }

  #pragma unroll
  for (int mi = 0; mi < 4; ++mi)
    #pragma unroll
    for (int ni = 0; ni < 4; ++ni)
      #pragma unroll
      for (int reg = 0; reg < 4; ++reg) {
        const int row = m0 + wr + mi * 16 + g * 4 + reg;
        const int col = n0 + wc + ni * 16 + li;
        const float v = (acc[mi][ni][reg] + bv[ni]) * scale;
        if (F32OUT) ((float*)outv)[(size_t)row * DM + col] = v;
        else ((_Float16*)outv + (size_t)z * 4096 * 1024)[(size_t)row * DM + col] = (_Float16)v;
      }
}

// ---------------- sliding-window attention: r21 + depth-2 V pipeline ----------------
// r21 structure (best, 161.0us) unchanged EXCEPT the PV loop: V loads for chunk cl+1
// are prefetched (clamped unconditional addresses, double-buffered, static indices)
// before chunk cl's GUARDED compute. Loads-only pipelining -- same mechanism as r21's
// QK fix; r22 showed un-guarding the compute itself regresses (+6us).
__global__ __launch_bounds__(256, 3) void k_attn(
    const _Float16* __restrict__ Q, const _Float16* __restrict__ K,
    const _Float16* __restrict__ Vt, float* __restrict__ Wout,
    _Float16* __restrict__ attb, int plane0, int nplanes)
{
  __shared__ float sred[4][16];
  __shared__ f32x4 ored[3][64][4];
  __shared__ _Float16 pw[16][584];
  if (blockIdx.x >= 128) {
    const int FBn = gridDim.x - 128;
    const int fb  = (blockIdx.x - 128) + FBn * (blockIdx.y + gridDim.y * blockIdx.z);
    zero_fill_role(Wout, plane0, nplanes, fb, FBn * gridDim.y * gridDim.z);
    return;
  }

  const int b = blockIdx.z, h = blockIdx.y;
  const int tid = threadIdx.x, lane = tid & 63, wid = tid >> 6;
  const int g = lane >> 4, li = lane & 15;
  const int qt = blockIdx.x;
  const int t0 = qt * 16;

  half8 qf[2];
  #pragma unroll
  for (int kk = 0; kk < 2; ++kk)
    qf[kk] = *(const half8*)(Q + (size_t)(b * SB + t0 + li) * DM + h * HD + kk * 32 + g * 8);

  const int kt_lo = qt - 32;
  const int d1 = kt_lo & 1;              // parity (1 for odd q-tiles)
  const int ktA0 = kt_lo - d1;           // even chunk base
  const _Float16* kb_ = K + (size_t)b * SB * DM + (size_t)h * HD;

  // chunk ownership: 17+d1 chunks over 4 waves (exact partition of slots [-d1, 34+d1))
  const int c_base = (wid == 0) ? 0 : (wid == 1) ? 5 : (wid == 2) ? (9 + d1) : (13 + d1);
  const int c_cnt  = (wid == 0) ? 5 : (wid == 1) ? (4 + d1) : 4;
  const int it_lo  = 2 * c_base - d1;
  const int it_n   = 2 * c_cnt;

  // ---- pass 1: QK with batched prefetch (5 tiles/batch, clamped addresses) ----
  half4 pp[10] = {};
  float s = 0.f;
  #pragma unroll
  for (int hb = 0; hb < 2; ++hb) {
    half8 kf[5][2];
    #pragma unroll
    for (int j = 0; j < 5; ++j) {
      int kt = kt_lo + it_lo + hb * 5 + j;
      kt = kt < 0 ? 0 : (kt > 127 ? 127 : kt);          // clamp -> unconditional load
      const _Float16* src = kb_ + (size_t)(kt * 16 + li) * DM + g * 8;
      kf[j][0] = *(const half8*)(src);
      kf[j][1] = *(const half8*)(src + 32);
    }
    #pragma unroll
    for (int j = 0; j < 5; ++j) {
      const int itl = hb * 5 + j;
      if (itl >= it_n) continue;                        // wave-uniform
      const int it = it_lo + itl;
      const int kt = kt_lo + it;
      const int scol = (it + d1) * 16 + g * 4;          // pw col of this slot
      if (it < 0 || it > 32 || kt < 0) {                // pad slot: exact zeros
        *(half4*)(&pw[li][scol]) = (half4){(_Float16)0.f, (_Float16)0.f, (_Float16)0.f, (_Float16)0.f};
        continue;
      }
      f32x4 a = {0.f, 0.f, 0.f, 0.f};
      a = __builtin_amdgcn_mfma_f32_16x16x32_f16(kf[j][0], qf[0], a, 0, 0, 0);
      a = __builtin_amdgcn_mfma_f32_16x16x32_f16(kf[j][1], qf[1], a, 0, 0, 0);
      float p0 = exp2f(a[0]), p1 = exp2f(a[1]), p2 = exp2f(a[2]), p3 = exp2f(a[3]);
      if (it == 0) {           // window tail: keep iff g*4+r > li
        p0 = (g * 4 + 0 > li) ? p0 : 0.f;
        p1 = (g * 4 + 1 > li) ? p1 : 0.f;
        p2 = (g * 4 + 2 > li) ? p2 : 0.f;
        p3 = (g * 4 + 3 > li) ? p3 : 0.f;
      }
      if (it == 32) {          // causal diagonal: keep iff g*4+r <= li
        p0 = (g * 4 + 0 <= li) ? p0 : 0.f;
        p1 = (g * 4 + 1 <= li) ? p1 : 0.f;
        p2 = (g * 4 + 2 <= li) ? p2 : 0.f;
        p3 = (g * 4 + 3 <= li) ? p3 : 0.f;
      }
      s += (p0 + p1) + (p2 + p3);
      half4 ph = {(_Float16)p0, (_Float16)p1, (_Float16)p2, (_Float16)p3};
      pp[itl] = ph;
      *(half4*)(&pw[li][scol]) = ph;
    }
  }

  // ---- cross-wave softmax denominator ----
  s += __shfl_xor(s, 16);
  s += __shfl_xor(s, 32);
  if (lane < 16) sred[wid][lane] = s;
  __syncthreads();
  const float rinv = 1.0f / (sred[0][li] + sred[1][li] + sred[2][li] + sred[3][li]);

  // ---- band writeback: full-line nt streaming (wave handles rows wid*4..wid*4+3) ----
  {
    float* wb = Wout + (size_t)(b * NH + h) * SB * SB;
    const int W4 = 136 + 8 * d1;        // 4-float chunks per row
    const int cs = ktA0 * 16;           // global col of pw col 0 (128B-aligned)
    #pragma unroll
    for (int rr = 0; rr < 4; ++rr) {
      const int r_ = wid * 4 + rr;
      const float rv = 1.0f / (sred[0][r_] + sred[1][r_] + sred[2][r_] + sred[3][r_]);
      float* dst = wb + (size_t)(t0 + r_) * SB;
      #pragma unroll
      for (int p = 0; p < 3; ++p) {
        const int idx = p * 64 + lane;
        if (idx < W4) {
          const int gc = cs + 4 * idx;
          if (gc >= 0 && gc < SB) {
            const half4 hv = *(const half4*)(&pw[r_][4 * idx]);
            f32x4 w = {(float)hv[0] * rv, (float)hv[1] * rv, (float)hv[2] * rv, (float)hv[3] * rv};
            __builtin_nontemporal_store(w, (f32x4*)(dst + gc));
          }
        }
      }
    }
  }

  // ---- PV with depth-2 V pipeline (loads unconditional+clamped, compute guarded) ----
  const _Float16* vb = Vt + (size_t)(b * NH + h) * HD * SB;
  f32x4 oacc[4] = {};
  half8 vfA[4], vfB[4];
  {
    int jb = (ktA0 + 2 * c_base) * 16 + g * 8;
    jb = jb < 0 ? 0 : (jb > SB - 8 ? SB - 8 : jb);
    #pragma unroll
    for (int dt = 0; dt < 4; ++dt)
      vfA[dt] = *(const half8*)(vb + (size_t)(dt * 16 + li) * SB + jb);
  }
  #pragma unroll
  for (int cl = 0; cl < 5; ++cl) {
    // prefetch next chunk's V (unconditional, clamped) into the other buffer
    if (cl < 4) {
      int jbn = (ktA0 + 2 * (c_base + cl + 1)) * 16 + g * 8;
      jbn = jbn < 0 ? 0 : (jbn > SB - 8 ? SB - 8 : jbn);
      if ((cl & 1) == 0) {
        #pragma unroll
        for (int dt = 0; dt < 4; ++dt)
          vfB[dt] = *(const half8*)(vb + (size_t)(dt * 16 + li) * SB + jbn);
      } else {
        #pragma unroll
        for (int dt = 0; dt < 4; ++dt)
          vfA[dt] = *(const half8*)(vb + (size_t)(dt * 16 + li) * SB + jbn);
      }
    }
    if (cl >= c_cnt) continue;                          // wave-uniform
    const int ktA = ktA0 + 2 * (c_base + cl);
    if (ktA + 1 < 0) continue;
    float pAf[4], pBf[4];
    #pragma unroll
    for (int r = 0; r < 4; ++r) { pAf[r] = (float)pp[2 * cl][r]; pBf[r] = (float)pp[2 * cl + 1][r]; }
    half8 pa;
    #pragma unroll
    for (int c8 = 0; c8 < 8; ++c8) {
      const int srcl = ((2 * (g & 1) + (c8 >> 2)) << 4) + li;
      const float va  = __shfl(pAf[c8 & 3], srcl);
      const float vb2 = __shfl(pBf[c8 & 3], srcl);
      pa[c8] = (_Float16)(g < 2 ? va : vb2);
    }
    if ((cl & 1) == 0) {
      #pragma unroll
      for (int dt = 0; dt < 4; ++dt)
        oacc[dt] = __builtin_amdgcn_mfma_f32_16x16x32_f16(pa, vfA[dt], oacc[dt], 0, 0, 0);
    } else {
      #pragma unroll
      for (int dt = 0; dt < 4; ++dt)
        oacc[dt] = __builtin_amdgcn_mfma_f32_16x16x32_f16(pa, vfB[dt], oacc[dt], 0, 0, 0);
    }
  }

  // ---- cross-wave PV reduction + output ----
  if (wid > 0) {
    #pragma unroll
    for (int dt = 0; dt < 4; ++dt) ored[wid - 1][lane][dt] = oacc[dt];
  }
  __syncthreads();
  if (wid == 0) {
    #pragma unroll
    for (int dt = 0; dt < 4; ++dt)
      oacc[dt] += ored[0][lane][dt] + ored[1][lane][dt] + ored[2][lane][dt];
    #pragma unroll
    for (int dt = 0; dt < 4; ++dt)
      #pragma unroll
      for (int r = 0; r < 4; ++r) {
        const float rr = __shfl(rinv, g * 4 + r);
        attb[(size_t)(b * SB + t0 + g * 4 + r) * DM + h * HD + dt * 16 + li] =
            (_Float16)(oacc[dt][r] * rr);
      }
  }
}

extern "C" void kernel_launch(void* const* d_in, const int* in_sizes, int n_in,
                              void* d_out, int out_size, void* d_ws, size_t ws_size,
                              hipStream_t stream) {
  (void)in_sizes; (void)n_in; (void)out_size; (void)ws_size;
  const float* x  = (const float*)d_in[0];
  const float* Wq = (const float*)d_in[1];
  const float* bq = (const float*)d_in[2];
  const float* Wk = (const float*)d_in[3];
  const float* bk = (const float*)d_in[4];
  const float* Wv = (const float*)d_in[5];
  const float* bv = (const float*)d_in[6];
  const float* Wo = (const float*)d_in[7];
  const float* bo = (const float*)d_in[8];

  char* ws = (char*)d_ws;
  _Float16* xh   = (_Float16*)(ws);                        // 8 MB
  _Float16* Wt   = (_Float16*)(ws + (size_t)8  * 1048576); // 8 MB
  _Float16* QKV  = (_Float16*)(ws + (size_t)16 * 1048576); // 16 MB (Q,K planes)
  _Float16* Vt   = (_Float16*)(ws + (size_t)32 * 1048576); // 8 MB
  _Float16* attb = (_Float16*)(ws + (size_t)40 * 1048576); // 8 MB

  float* out   = (float*)d_out;
  float* Wattn = out + (size_t)2 * SB * DM;   // attention-weights output region

  // Q pre-scaled by 0.125*log2(e) so attention can use exp2 directly.
  const float qscale = 0.125f * 1.4426950408889634f;
  const _Float16* Kp = QKV + (size_t)4096 * 1024;

  k_pre<<<dim3(3072), dim3(256), 0, stream>>>(x, Wq, Wk, Wv, Wo, xh, Wt);
  // QKV GEMM (768 compute blocks) + 192 fill blocks, planes [0,12)
  k_gemm<false><<<dim3(40, 8, 3), dim3(256), 0, stream>>>(xh, Wt, bq, bk, bv, (void*)QKV, Vt, qscale, Wattn, 0, 12);
  // attn (4096 compute blocks) + 512 fill blocks, planes [12,24)
  k_attn<<<dim3(144, 16, 2), dim3(256), 0, stream>>>(QKV, Kp, Vt, Wattn, attb, 12, 12);
  // O GEMM (256 compute blocks) + 128 fill blocks, planes [24,32)
  k_gemm<true><<<dim3(48, 8, 1), dim3(256), 0, stream>>>(attb, Wt + (size_t)3 * DM * DM, bo, bo, bo, (void*)out, nullptr, 1.0f, Wattn, 24, 8);
}

// Round 24
// 160.560 us; speedup vs baseline: 1.0388x; 1.0300x over previous
//
#include <hip/hip_runtime.h>
#include <cstdint>
#include <cstddef>

#define NH  16
#define HD  64
#define DM  1024
#define SB  2048
#define WIN 512

typedef _Float16 half8  __attribute__((ext_vector_type(8)));
typedef _Float16 half4  __attribute__((ext_vector_type(4)));
typedef float    f32x4  __attribute__((ext_vector_type(4)));

// global_load_lds: LDS dest must be WAVE-UNIFORM (hw adds lane*16); global src is per-lane.
#define GLL16(gp, lp) __builtin_amdgcn_global_load_lds( \
    (const __attribute__((address_space(1))) void*)(gp), \
    (__attribute__((address_space(3))) void*)(lp), 16, 0, 0)

// Zero-fill of the out-of-band region. Boundaries 128B-aligned to match the
// attn band writes: lo = t0-512-16*par, hi = t0+32+16*par (par = q-tile parity).
__device__ __forceinline__ void zero_fill_role(float* zbase, int plane0, int nplanes,
                                               int fb, int nfb) {
  const int nrows = nplanes << 11;
  const f32x4 z4 = {0.f, 0.f, 0.f, 0.f};
  const int tid = threadIdx.x;
  const int step = blockDim.x * 4;
  for (int rr = fb; rr < nrows; rr += nfb) {
    const int bh = plane0 + (rr >> 11), i = rr & 2047;
    float* rowp = zbase + ((size_t)bh << 22) + ((size_t)i << 11);
    const int t0i = i & ~15;
    const int par = (t0i >> 4) & 1;
    int lo = t0i - 512 - 16 * par; if (lo < 0) lo = 0;
    int hi = t0i + 32 + 16 * par;  if (hi > SB) hi = SB;
    for (int c = tid * 4; c < lo; c += step)
      __builtin_nontemporal_store(z4, (f32x4*)(rowp + c));
    for (int c = hi + tid * 4; c < SB; c += step)
      __builtin_nontemporal_store(z4, (f32x4*)(rowp + c));
  }
}

// ---------------- merged preprocessing: x f32->f16, W f32->f16 transposed ----------------
__global__ void k_pre(const float* __restrict__ x,
                      const float* __restrict__ Wq, const float* __restrict__ Wk,
                      const float* __restrict__ Wv, const float* __restrict__ Wo,
                      _Float16* __restrict__ xh, _Float16* __restrict__ Wt) {
  __shared__ float t[64][68];
  const int bid = blockIdx.x, tid = threadIdx.x;
  if (bid < 2048) {
    const int i = (bid * 256 + tid) * 8;
    const float4 a = *(const float4*)(x + i);
    const float4 b = *(const float4*)(x + i + 4);
    half8 o = { (_Float16)a.x, (_Float16)a.y, (_Float16)a.z, (_Float16)a.w,
                (_Float16)b.x, (_Float16)b.y, (_Float16)b.z, (_Float16)b.w };
    *(half8*)(xh + i) = o;
    return;
  }
  const int tt = bid - 2048;
  const int z = tt >> 8, r2 = tt & 255;
  const int k0 = (r2 >> 4) * 64, n0 = (r2 & 15) * 64;
  const float* src = (z == 0) ? Wq : (z == 1) ? Wk : (z == 2) ? Wv : Wo;
  _Float16* dst = Wt + (size_t)z * DM * DM;
  #pragma unroll
  for (int i = 0; i < 4; ++i) {
    const int idx = i * 1024 + tid * 4;
    const int r = idx >> 6, c = idx & 63;
    const float4 v = *(const float4*)(src + (size_t)(k0 + r) * DM + n0 + c);
    *(float4*)(&t[r][c]) = v;
  }
  __syncthreads();
  #pragma unroll
  for (int i = 0; i < 4; ++i) {
    const int idx = i * 1024 + tid * 4;
    const int nr = idx >> 6, kc = idx & 63;
    half4 o = { (_Float16)t[kc + 0][nr], (_Float16)t[kc + 1][nr],
                (_Float16)t[kc + 2][nr], (_Float16)t[kc + 3][nr] };
    *(half4*)(dst + (size_t)(n0 + nr) * DM + k0 + kc) = o;
  }
}

// ---------------- GEMM: C[M,N] = A[M,K]h * Wt[N,K]h + bias; M=4096,N=K=1024 ----------------
template<bool F32OUT>
__global__ __launch_bounds__(256, 4) void k_gemm(
    const _Float16* __restrict__ A, const _Float16* __restrict__ Wt,
    const float* __restrict__ b0, const float* __restrict__ b1, const float* __restrict__ b2,
    void* __restrict__ outv, _Float16* __restrict__ Vt, float scale0,
    float* __restrict__ zbase, int plane0, int nplanes)
{
  __shared__ _Float16 As[128 * 64];
  __shared__ _Float16 Bs[128 * 64];
  if (blockIdx.x >= 32) {
    const int FBn = gridDim.x - 32;
    const int fb  = (blockIdx.x - 32) + FBn * (blockIdx.y + gridDim.y * blockIdx.z);
    zero_fill_role(zbase, plane0, nplanes, fb, FBn * gridDim.y * gridDim.z);
    return;
  }

  const int z = blockIdx.z;
  const _Float16* Wz = Wt + (size_t)z * DM * DM;
  const float* bias = (z == 0) ? b0 : (z == 1) ? b1 : b2;
  const float scale = (z == 0) ? scale0 : 1.0f;
  const int m0 = blockIdx.x * 128, n0 = blockIdx.y * 128;
  const int tid = threadIdx.x, lane = tid & 63, wid = tid >> 6;
  const int g = lane >> 4, li = lane & 15;
  const int wr = (wid & 1) * 64, wc = (wid >> 1) * 64;

  f32x4 acc[4][4] = {};

  for (int kt = 0; kt < 16; ++kt) {
    const int kb = kt * 64;
    #pragma unroll
    for (int i = 0; i < 4; ++i) {
      const int c = wid + 4 * i;
      const int off = c * 1024 + lane * 16;
      const int r = off >> 7;
      const int cb = off & 127;
      const int sc_ = cb ^ ((r & 7) << 4);
      GLL16(A  + (size_t)(m0 + r) * DM + kb + (sc_ >> 1), (char*)As + c * 1024);
      GLL16(Wz + (size_t)(n0 + r) * DM + kb + (sc_ >> 1), (char*)Bs + c * 1024);
    }
    __syncthreads();
    #pragma unroll
    for (int kk = 0; kk < 2; ++kk) {
      half8 bf[4];
      #pragma unroll
      for (int ni = 0; ni < 4; ++ni) {
        const int r = wc + ni * 16 + li;
        const int cbyte = (kk * 64 + g * 16) ^ ((r & 7) << 4);
        bf[ni] = *(const half8*)((const char*)Bs + r * 128 + cbyte);
      }
      #pragma unroll
      for (int mi = 0; mi < 4; ++mi) {
        const int r = wr + mi * 16 + li;
        const int cbyte = (kk * 64 + g * 16) ^ ((r & 7) << 4);
        const half8 af = *(const half8*)((const char*)As + r * 128 + cbyte);
        #pragma unroll
        for (int ni = 0; ni < 4; ++ni)
          acc[mi][ni] = __builtin_amdgcn_mfma_f32_16x16x32_f16(af, bf[ni], acc[mi][ni], 0, 0, 0);
      }
    }
    __syncthreads();
  }

  float bv[4];
  #pragma unroll
  for (int ni = 0; ni < 4; ++ni) bv[ni] = bias[n0 + wc + ni * 16 + li];

  if (!F32OUT && z == 2) {
    #pragma unroll
    for (int mi = 0; mi < 4; ++mi)
      #pragma unroll
      for (int ni = 0; ni < 4; ++ni) {
        const int col = n0 + wc + ni * 16 + li;
        const int h2 = col >> 6, d = col & 63;
        const int row0 = m0 + wr + mi * 16 + g * 4;
        const int bb = row0 >> 11, s0 = row0 & 2047;
        half4 o = { (_Float16)(acc[mi][ni][0] + bv[ni]), (_Float16)(acc[mi][ni][1] + bv[ni]),
                    (_Float16)(acc[mi][ni][2] + bv[ni]), (_Float16)(acc[mi][ni][3] + bv[ni]) };
        *(half4*)(Vt + (size_t)((bb * NH + h2) * HD + d) * SB + s0) = o;
      }
    return;
  }

  #pragma unroll
  for (int mi = 0; mi < 4; ++mi)
    #pragma unroll
    for (int ni = 0; ni < 4; ++ni)
      #pragma unroll
      for (int reg = 0; reg < 4; ++reg) {
        const int row = m0 + wr + mi * 16 + g * 4 + reg;
        const int col = n0 + wc + ni * 16 + li;
        const float v = (acc[mi][ni][reg] + bv[ni]) * scale;
        if (F32OUT) ((float*)outv)[(size_t)row * DM + col] = v;
        else ((_Float16*)outv + (size_t)z * 4096 * 1024)[(size_t)row * DM + col] = (_Float16)v;
      }
}

// ---------------- sliding-window attention (r21 structure — session best) ----------------
// QK loads batched 5 tiles ahead with clamped unconditional addresses (2 latency
// exposures instead of 10); compute remains wave-uniform-guarded (r22/r23 showed
// un-guarding or pipelining the PV side regresses). LDS band tile + full-line nt
// writeback; fill split 12/12/8 across the three heavy dispatches.
__global__ __launch_bounds__(256, 3) void k_attn(
    const _Float16* __restrict__ Q, const _Float16* __restrict__ K,
    const _Float16* __restrict__ Vt, float* __restrict__ Wout,
    _Float16* __restrict__ attb, int plane0, int nplanes)
{
  __shared__ float sred[4][16];
  __shared__ f32x4 ored[3][64][4];
  __shared__ _Float16 pw[16][584];
  if (blockIdx.x >= 128) {
    const int FBn = gridDim.x - 128;
    const int fb  = (blockIdx.x - 128) + FBn * (blockIdx.y + gridDim.y * blockIdx.z);
    zero_fill_role(Wout, plane0, nplanes, fb, FBn * gridDim.y * gridDim.z);
    return;
  }

  const int b = blockIdx.z, h = blockIdx.y;
  const int tid = threadIdx.x, lane = tid & 63, wid = tid >> 6;
  const int g = lane >> 4, li = lane & 15;
  const int qt = blockIdx.x;
  const int t0 = qt * 16;

  half8 qf[2];
  #pragma unroll
  for (int kk = 0; kk < 2; ++kk)
    qf[kk] = *(const half8*)(Q + (size_t)(b * SB + t0 + li) * DM + h * HD + kk * 32 + g * 8);

  const int kt_lo = qt - 32;
  const int d1 = kt_lo & 1;              // parity (1 for odd q-tiles)
  const int ktA0 = kt_lo - d1;           // even chunk base
  const _Float16* kb_ = K + (size_t)b * SB * DM + (size_t)h * HD;

  // chunk ownership: 17+d1 chunks over 4 waves (exact partition of slots [-d1, 34+d1))
  const int c_base = (wid == 0) ? 0 : (wid == 1) ? 5 : (wid == 2) ? (9 + d1) : (13 + d1);
  const int c_cnt  = (wid == 0) ? 5 : (wid == 1) ? (4 + d1) : 4;
  const int it_lo  = 2 * c_base - d1;
  const int it_n   = 2 * c_cnt;

  // ---- pass 1: QK with batched prefetch (5 tiles/batch, clamped addresses) ----
  half4 pp[10] = {};
  float s = 0.f;
  #pragma unroll
  for (int hb = 0; hb < 2; ++hb) {
    half8 kf[5][2];
    #pragma unroll
    for (int j = 0; j < 5; ++j) {
      int kt = kt_lo + it_lo + hb * 5 + j;
      kt = kt < 0 ? 0 : (kt > 127 ? 127 : kt);          // clamp -> unconditional load
      const _Float16* src = kb_ + (size_t)(kt * 16 + li) * DM + g * 8;
      kf[j][0] = *(const half8*)(src);
      kf[j][1] = *(const half8*)(src + 32);
    }
    #pragma unroll
    for (int j = 0; j < 5; ++j) {
      const int itl = hb * 5 + j;
      if (itl >= it_n) continue;                        // wave-uniform
      const int it = it_lo + itl;
      const int kt = kt_lo + it;
      const int scol = (it + d1) * 16 + g * 4;          // pw col of this slot
      if (it < 0 || it > 32 || kt < 0) {                // pad slot: exact zeros
        *(half4*)(&pw[li][scol]) = (half4){(_Float16)0.f, (_Float16)0.f, (_Float16)0.f, (_Float16)0.f};
        continue;
      }
      f32x4 a = {0.f, 0.f, 0.f, 0.f};
      a = __builtin_amdgcn_mfma_f32_16x16x32_f16(kf[j][0], qf[0], a, 0, 0, 0);
      a = __builtin_amdgcn_mfma_f32_16x16x32_f16(kf[j][1], qf[1], a, 0, 0, 0);
      float p0 = exp2f(a[0]), p1 = exp2f(a[1]), p2 = exp2f(a[2]), p3 = exp2f(a[3]);
      if (it == 0) {           // window tail: keep iff g*4+r > li
        p0 = (g * 4 + 0 > li) ? p0 : 0.f;
        p1 = (g * 4 + 1 > li) ? p1 : 0.f;
        p2 = (g * 4 + 2 > li) ? p2 : 0.f;
        p3 = (g * 4 + 3 > li) ? p3 : 0.f;
      }
      if (it == 32) {          // causal diagonal: keep iff g*4+r <= li
        p0 = (g * 4 + 0 <= li) ? p0 : 0.f;
        p1 = (g * 4 + 1 <= li) ? p1 : 0.f;
        p2 = (g * 4 + 2 <= li) ? p2 : 0.f;
        p3 = (g * 4 + 3 <= li) ? p3 : 0.f;
      }
      s += (p0 + p1) + (p2 + p3);
      half4 ph = {(_Float16)p0, (_Float16)p1, (_Float16)p2, (_Float16)p3};
      pp[itl] = ph;
      *(half4*)(&pw[li][scol]) = ph;
    }
  }

  // ---- cross-wave softmax denominator ----
  s += __shfl_xor(s, 16);
  s += __shfl_xor(s, 32);
  if (lane < 16) sred[wid][lane] = s;
  __syncthreads();
  const float rinv = 1.0f / (sred[0][li] + sred[1][li] + sred[2][li] + sred[3][li]);

  // ---- band writeback: full-line nt streaming (wave handles rows wid*4..wid*4+3) ----
  {
    float* wb = Wout + (size_t)(b * NH + h) * SB * SB;
    const int W4 = 136 + 8 * d1;        // 4-float chunks per row
    const int cs = ktA0 * 16;           // global col of pw col 0 (128B-aligned)
    #pragma unroll
    for (int rr = 0; rr < 4; ++rr) {
      const int r_ = wid * 4 + rr;
      const float rv = 1.0f / (sred[0][r_] + sred[1][r_] + sred[2][r_] + sred[3][r_]);
      float* dst = wb + (size_t)(t0 + r_) * SB;
      #pragma unroll
      for (int p = 0; p < 3; ++p) {
        const int idx = p * 64 + lane;
        if (idx < W4) {
          const int gc = cs + 4 * idx;
          if (gc >= 0 && gc < SB) {
            const half4 hv = *(const half4*)(&pw[r_][4 * idx]);
            f32x4 w = {(float)hv[0] * rv, (float)hv[1] * rv, (float)hv[2] * rv, (float)hv[3] * rv};
            __builtin_nontemporal_store(w, (f32x4*)(dst + gc));
          }
        }
      }
    }
  }

  // ---- PV over this wave's chunks (raw p, rinv deferred to epilogue) ----
  const _Float16* vb = Vt + (size_t)(b * NH + h) * HD * SB;
  f32x4 oacc[4] = {};
  #pragma unroll
  for (int cl = 0; cl < 5; ++cl) {
    if (cl >= c_cnt) continue;
    const int ktA = ktA0 + 2 * (c_base + cl);
    if (ktA + 1 < 0) continue;
    float pAf[4], pBf[4];
    #pragma unroll
    for (int r = 0; r < 4; ++r) { pAf[r] = (float)pp[2 * cl][r]; pBf[r] = (float)pp[2 * cl + 1][r]; }
    half8 pa;
    #pragma unroll
    for (int c8 = 0; c8 < 8; ++c8) {
      const int srcl = ((2 * (g & 1) + (c8 >> 2)) << 4) + li;
      const float va  = __shfl(pAf[c8 & 3], srcl);
      const float vb2 = __shfl(pBf[c8 & 3], srcl);
      pa[c8] = (_Float16)(g < 2 ? va : vb2);
    }
    int jb = ktA * 16 + g * 8;
    jb = jb < 0 ? 0 : (jb > SB - 8 ? SB - 8 : jb);
    #pragma unroll
    for (int dt = 0; dt < 4; ++dt) {
      half8 vf = *(const half8*)(vb + (size_t)(dt * 16 + li) * SB + jb);
      oacc[dt] = __builtin_amdgcn_mfma_f32_16x16x32_f16(pa, vf, oacc[dt], 0, 0, 0);
    }
  }

  // ---- cross-wave PV reduction + output ----
  if (wid > 0) {
    #pragma unroll
    for (int dt = 0; dt < 4; ++dt) ored[wid - 1][lane][dt] = oacc[dt];
  }
  __syncthreads();
  if (wid == 0) {
    #pragma unroll
    for (int dt = 0; dt < 4; ++dt)
      oacc[dt] += ored[0][lane][dt] + ored[1][lane][dt] + ored[2][lane][dt];
    #pragma unroll
    for (int dt = 0; dt < 4; ++dt)
      #pragma unroll
      for (int r = 0; r < 4; ++r) {
        const float rr = __shfl(rinv, g * 4 + r);
        attb[(size_t)(b * SB + t0 + g * 4 + r) * DM + h * HD + dt * 16 + li] =
            (_Float16)(oacc[dt][r] * rr);
      }
  }
}

extern "C" void kernel_launch(void* const* d_in, const int* in_sizes, int n_in,
                              void* d_out, int out_size, void* d_ws, size_t ws_size,
                              hipStream_t stream) {
  (void)in_sizes; (void)n_in; (void)out_size; (void)ws_size;
  const float* x  = (const float*)d_in[0];
  const float* Wq = (const float*)d_in[1];
  const float* bq = (const float*)d_in[2];
  const float* Wk = (const float*)d_in[3];
  const float* bk = (const float*)d_in[4];
  const float* Wv = (const float*)d_in[5];
  const float* bv = (const float*)d_in[6];
  const float* Wo = (const float*)d_in[7];
  const float* bo = (const float*)d_in[8];

  char* ws = (char*)d_ws;
  _Float16* xh   = (_Float16*)(ws);                        // 8 MB
  _Float16* Wt   = (_Float16*)(ws + (size_t)8  * 1048576); // 8 MB
  _Float16* QKV  = (_Float16*)(ws + (size_t)16 * 1048576); // 16 MB (Q,K planes)
  _Float16* Vt   = (_Float16*)(ws + (size_t)32 * 1048576); // 8 MB
  _Float16* attb = (_Float16*)(ws + (size_t)40 * 1048576); // 8 MB

  float* out   = (float*)d_out;
  float* Wattn = out + (size_t)2 * SB * DM;   // attention-weights output region

  // Q pre-scaled by 0.125*log2(e) so attention can use exp2 directly.
  const float qscale = 0.125f * 1.4426950408889634f;
  const _Float16* Kp = QKV + (size_t)4096 * 1024;

  k_pre<<<dim3(3072), dim3(256), 0, stream>>>(x, Wq, Wk, Wv, Wo, xh, Wt);
  // QKV GEMM (768 compute blocks) + 192 fill blocks, planes [0,12)
  k_gemm<false><<<dim3(40, 8, 3), dim3(256), 0, stream>>>(xh, Wt, bq, bk, bv, (void*)QKV, Vt, qscale, Wattn, 0, 12);
  // attn (4096 compute blocks) + 512 fill blocks, planes [12,24)
  k_attn<<<dim3(144, 16, 2), dim3(256), 0, stream>>>(QKV, Kp, Vt, Wattn, attb, 12, 12);
  // O GEMM (256 compute blocks) + 128 fill blocks, planes [24,32)
  k_gemm<true><<<dim3(48, 8, 1), dim3(256), 0, stream>>>(attb, Wt + (size_t)3 * DM * DM, bo, bo, bo, (void*)out, nullptr, 1.0f, Wattn, 24, 8);
}